// Round 12
// baseline (580.697 us; speedup 1.0000x reference)
//
#include <hip/hip_runtime.h>

// Problem: VOCAB=10000, EMB=100, T=80, UNITS=256, BATCH=4096 — ALL FP32 I/O.
// out = sigmoid(h2_T);  h_l,t = tanh(x_l,t @ Wl + h_l,t-1 @ Ul + bl)
#define BATCH 4096
#define TLEN  80
#define EMBD  100
#define UNITS 256
#define EMB_PAD 128            // emb K padded to 4 k-tiles of 32

typedef _Float16 f16;
typedef __attribute__((ext_vector_type(8))) _Float16 h8;   // 8 f16 = 4 VGPR MFMA A/B frag
typedef __attribute__((ext_vector_type(4))) float f32x4;   // MFMA C/D frag

__device__ __forceinline__ float fast_tanh(float x) {
  x = fminf(fmaxf(x, -15.f), 15.f);
  float e = __expf(-2.f * x);
  return (1.f - e) / (1.f + e);
}
__device__ __forceinline__ float fast_sigmoid(float x) {
  x = fminf(fmaxf(x, -30.f), 30.f);
  return 1.f / (1.f + __expf(-x));
}

// ---------------- workspace layout (3.02 MB; < 4 MB per-XCD L2 — r10 lesson:
// 6.9 MB hot set thrashed L2, 3.0 MB hits ~99.6%) ---------------------------
// B-frag layout (16x16x32, r7-verified, dtype-independent): lane holds
// B[k=quad*8+j][n=lane&15]; 8 contiguous f16 per (ktg,nt,lane) -> one dwordx4.
// ktg slots: W1 (K pad 128) = 0..3, U1 = 4..11, W2 = 12..19, U2 = 20..27.
#define KT_ALL 28
#define OFF_EHF ((size_t)0)
#define EHF_BYTES ((size_t)10000 * EMB_PAD * 2)             // 2,560,000
#define OFF_WF  EHF_BYTES
#define WF_BYTES ((size_t)KT_ALL * 16 * 64 * 8 * 2)         //   458,752
#define WS_NEED (OFF_WF + WF_BYTES)                          // 3,018,752 B

__device__ __forceinline__ size_t fidx(int ktg, int nt, int lane) {
  return (((size_t)ktg * 16 + nt) * 64 + lane) * 8;
}

// ---------------- precompute: weights -> swizzled fp16 B-frags (r10-verified)
__global__ __launch_bounds__(256) void k_split_w16(
    const float* __restrict__ W1, const float* __restrict__ U1,
    const float* __restrict__ W2, const float* __restrict__ U2,
    f16* __restrict__ wf)
{
  int gid = blockIdx.x * 256 + threadIdx.x;           // one per (ktg,nt,lane)
  if (gid >= KT_ALL * 16 * 64) return;
  int lane = gid & 63, nt = (gid >> 6) & 15, ktg = gid >> 10;
  const float* M; int Kact, ktl;
  if (ktg < 4)       { M = W1; Kact = EMBD;  ktl = ktg;      }
  else if (ktg < 12) { M = U1; Kact = UNITS; ktl = ktg - 4;  }
  else if (ktg < 20) { M = W2; Kact = UNITS; ktl = ktg - 12; }
  else               { M = U2; Kact = UNITS; ktl = ktg - 20; }
  int n = nt * 16 + (lane & 15);
  int kb = ktl * 32 + (lane >> 4) * 8;
  size_t base = fidx(ktg, nt, lane);
#pragma unroll
  for (int j = 0; j < 8; ++j) {
    int k = kb + j;
    wf[base + j] = (f16)((k < Kact) ? M[(size_t)k * UNITS + n] : 0.f);  // RNE
  }
}

// ---------------- precompute: emb -> padded fp16 (r10-verified) -------------
__global__ __launch_bounds__(256) void k_split_emb16(
    const float* __restrict__ emb, f16* __restrict__ ehf)
{
  int gid = blockIdx.x * 256 + threadIdx.x;
  if (gid >= 10000 * EMB_PAD) return;
  int row = gid >> 7, kk = gid & (EMB_PAD - 1);
  ehf[gid] = (f16)((kk < EMBD) ? emb[row * EMBD + kk] : 0.f);
}

#define MFMA16(A, B, C) __builtin_amdgcn_mfma_f32_16x16x32_f16(A, B, C, 0, 0, 0)

// store tanh result into next-step A-frag (single f16; layout r7-verified):
// elem (row=m, col=k): kt=col>>5, lane'=((col>>3)&3)*16+row, j'=col&7
__device__ __forceinline__ void store_frag1(f16* __restrict__ f, int col, int row, float v) {
  int a = (col >> 5) * 512 + (((col >> 3) & 3) * 16 + row) * 8 + (col & 7);
  f[a] = (f16)v;
}

// ---------------------------------------------------------------------------
// Main kernel v6 = r11 structure with the VGPR budget FIXED.
// __launch_bounds__(1024, 1): 1024-thr block forces 4 waves/SIMD co-resident,
// min-1-wave/EU removes the occupancy-driven 64-VGPR cap -> allocator may use
// up to 512/wave; the 28 persistent B-frags (112 VGPR) + working set (~80)
// actually stay register-resident this time (r11: VGPR_Count=64 proved they
// were demoted to per-step L1 reloads = 448 KB/CU-step = the 544 us wall).
// In-loop global traffic after fix: 4-frag emb gather only (64 KB/CU-step).
// ---------------------------------------------------------------------------
__global__ __launch_bounds__(1024, 1) void rnn_ws2(
    const int* __restrict__ idx, const f16* __restrict__ ehf,
    const f16* __restrict__ wf,
    const float* __restrict__ b1, const float* __restrict__ b2,
    float* __restrict__ out)
{
  __shared__ __align__(16) f16 f1[2][4096];   // [buf][kt*512 + lane*8 + j]
  __shared__ __align__(16) f16 f2[2][4096];

  const int tid  = threadIdx.x;
  const int lane = tid & 63;
  const int w    = tid >> 6;          // wave 0..15 = its n-tile
  const int m    = lane & 15;
  const int q    = lane >> 4;
  const int col0 = w * 16 + m;
  const int b0   = blockIdx.x * 16;

  const float bias1 = b1[col0];
  const float bias2 = b2[col0];
  const int* tokp = idx + (size_t)(b0 + m) * TLEN;

  // -------- persistent weight fragments: loaded once, live in VGPRs --------
  h8 Bx[4], Bu1[8], Bw2[8], Bu2[8];
#pragma unroll
  for (int kt = 0; kt < 4; ++kt) Bx[kt]  = *(const h8*)(wf + fidx(kt,      w, lane));
#pragma unroll
  for (int kt = 0; kt < 8; ++kt) Bu1[kt] = *(const h8*)(wf + fidx(4  + kt, w, lane));
#pragma unroll
  for (int kt = 0; kt < 8; ++kt) Bw2[kt] = *(const h8*)(wf + fidx(12 + kt, w, lane));
#pragma unroll
  for (int kt = 0; kt < 8; ++kt) Bu2[kt] = *(const h8*)(wf + fidx(20 + kt, w, lane));

  // t=0 embedding fragment (A-operand rows = this lane's token row m)
  h8 Ax[4];
  {
    const f16* eh = ehf + (size_t)tokp[0] * EMB_PAD + q * 8;
#pragma unroll
    for (int kt = 0; kt < 4; ++kt) Ax[kt] = *(const h8*)(eh + kt * 32);
  }

  for (int i = tid; i < 4096; i += 1024) {
    f1[0][i] = (f16)0.f;
    f2[0][i] = (f16)0.f;
  }
  __syncthreads();

  for (int t = 0; t < TLEN; ++t) {
    const int p = t & 1, qb = p ^ 1;

    // ---- layer 1: a1 = b1 + x_t @ W1 + h1_old @ U1  (two indep chains) ----
    f32x4 accA = (f32x4){0.f, 0.f, 0.f, 0.f};
    f32x4 accB = (f32x4){0.f, 0.f, 0.f, 0.f};
#pragma unroll
    for (int kt = 0; kt < 4; ++kt)
      accA = MFMA16(Ax[kt], Bx[kt], accA);
#pragma unroll
    for (int kt = 0; kt < 8; ++kt) {
      h8 ah = *(const h8*)&f1[p][kt * 512 + lane * 8];
      if (kt & 1) accA = MFMA16(ah, Bu1[kt], accA);
      else        accB = MFMA16(ah, Bu1[kt], accB);
    }
#pragma unroll
    for (int r = 0; r < 4; ++r)
      store_frag1(f1[qb], col0, q * 4 + r, fast_tanh(accA[r] + accB[r] + bias1));

    // ---- layer 2 pre-barrier half: h2_old @ U2 (independent of f1[qb]) ----
    f32x4 acc2a = (f32x4){0.f, 0.f, 0.f, 0.f};
    f32x4 acc2b = (f32x4){0.f, 0.f, 0.f, 0.f};
#pragma unroll
    for (int kt = 0; kt < 8; ++kt) {
      h8 ah = *(const h8*)&f2[p][kt * 512 + lane * 8];
      if (kt & 1) acc2a = MFMA16(ah, Bu2[kt], acc2a);
      else        acc2b = MFMA16(ah, Bu2[kt], acc2b);
    }
    __syncthreads();                           // barrier 1: f1[qb] visible

    // ---- layer 2 post-barrier half: h1_new @ W2 ----
#pragma unroll
    for (int kt = 0; kt < 8; ++kt) {
      h8 ah = *(const h8*)&f1[qb][kt * 512 + lane * 8];
      if (kt & 1) acc2a = MFMA16(ah, Bw2[kt], acc2a);
      else        acc2b = MFMA16(ah, Bw2[kt], acc2b);
    }
    // prefetch next step's embedding fragment (hidden under epilogue+barrier)
    if (t + 1 < TLEN) {
      const f16* eh = ehf + (size_t)tokp[t + 1] * EMB_PAD + q * 8;
#pragma unroll
      for (int kt = 0; kt < 4; ++kt) Ax[kt] = *(const h8*)(eh + kt * 32);
    }
#pragma unroll
    for (int r = 0; r < 4; ++r) {
      int row = q * 4 + r;
      float tv = fast_tanh(acc2a[r] + acc2b[r] + bias2);
      store_frag1(f2[qb], col0, row, tv);
      if (t == TLEN - 1)
        out[(size_t)(b0 + row) * UNITS + col0] = fast_sigmoid(tv);
    }
    __syncthreads();                           // barrier 2: f2[qb] visible
  }
}

// ---------------------------------------------------------------------------
extern "C" void kernel_launch(void* const* d_in, const int* in_sizes, int n_in,
                              void* d_out, int out_size, void* d_ws, size_t ws_size,
                              hipStream_t stream)
{
  const int*   idx = (const int*)d_in[0];
  const float* emb = (const float*)d_in[1];
  const float* W1  = (const float*)d_in[2];
  const float* U1  = (const float*)d_in[3];
  const float* b1  = (const float*)d_in[4];
  const float* W2  = (const float*)d_in[5];
  const float* U2  = (const float*)d_in[6];
  const float* b2  = (const float*)d_in[7];
  // d_in[8] (Wd), d_in[9] (bd) dead in the reference output.
  float* out = (float*)d_out;

  // WS_NEED = 3.02 MB < 6.04 MB proven available (r7); < 4 MB L2 per XCD.
  f16* ehf = (f16*)((char*)d_ws + OFF_EHF);
  f16* wf  = (f16*)((char*)d_ws + OFF_WF);
  k_split_emb16<<<(10000 * EMB_PAD + 255) / 256, 256, 0, stream>>>(emb, ehf);
  k_split_w16<<<(KT_ALL * 16 * 64 + 255) / 256, 256, 0, stream>>>(W1, U1, W2, U2, wf);
  rnn_ws2<<<BATCH / 16, 1024, 0, stream>>>(idx, ehf, wf, b1, b2, out);
}

// Round 13
// 518.799 us; speedup vs baseline: 1.1193x; 1.1193x over previous
//
#include <hip/hip_runtime.h>

// Problem: VOCAB=10000, EMB=100, T=80, UNITS=256, BATCH=4096 — ALL FP32 I/O.
// out = sigmoid(h2_T);  h_l,t = tanh(x_l,t @ Wl + h_l,t-1 @ Ul + bl)
#define BATCH 4096
#define TLEN  80
#define EMBD  100
#define UNITS 256
#define EMB_PAD 128            // emb K padded to 4 k-tiles of 32

typedef _Float16 f16;
typedef __attribute__((ext_vector_type(8))) _Float16 h8;   // 8 f16 = 4 VGPR MFMA A/B frag
typedef __attribute__((ext_vector_type(4))) float f32x4;   // MFMA C/D frag

__device__ __forceinline__ float fast_tanh(float x) {
  x = fminf(fmaxf(x, -15.f), 15.f);
  float e = __expf(-2.f * x);
  return (1.f - e) / (1.f + e);
}
__device__ __forceinline__ float fast_sigmoid(float x) {
  x = fminf(fmaxf(x, -30.f), 30.f);
  return 1.f / (1.f + __expf(-x));
}

// ---------------- workspace layout (3.02 MB; < 4 MB per-XCD L2 — r10 lesson:
// 6.9 MB hot set thrashed L2, 3.0 MB hits ~99.6%) ---------------------------
// B-frag layout (16x16x32, r7-verified, dtype-independent): lane holds
// B[k=quad*8+j][n=lane&15]; 8 contiguous f16 per (ktg,nt,lane) -> one dwordx4.
// ktg slots: W1 (K pad 128) = 0..3, U1 = 4..11, W2 = 12..19, U2 = 20..27.
#define KT_ALL 28
#define OFF_EHF ((size_t)0)
#define EHF_BYTES ((size_t)10000 * EMB_PAD * 2)             // 2,560,000
#define OFF_WF  EHF_BYTES
#define WF_BYTES ((size_t)KT_ALL * 16 * 64 * 8 * 2)         //   458,752
#define WS_NEED (OFF_WF + WF_BYTES)                          // 3,018,752 B

__device__ __forceinline__ size_t fidx(int ktg, int nt, int lane) {
  return (((size_t)ktg * 16 + nt) * 64 + lane) * 8;
}

// ---------------- precompute: weights -> swizzled fp16 B-frags (r10-verified)
__global__ __launch_bounds__(256) void k_split_w16(
    const float* __restrict__ W1, const float* __restrict__ U1,
    const float* __restrict__ W2, const float* __restrict__ U2,
    f16* __restrict__ wf)
{
  int gid = blockIdx.x * 256 + threadIdx.x;           // one per (ktg,nt,lane)
  if (gid >= KT_ALL * 16 * 64) return;
  int lane = gid & 63, nt = (gid >> 6) & 15, ktg = gid >> 10;
  const float* M; int Kact, ktl;
  if (ktg < 4)       { M = W1; Kact = EMBD;  ktl = ktg;      }
  else if (ktg < 12) { M = U1; Kact = UNITS; ktl = ktg - 4;  }
  else if (ktg < 20) { M = W2; Kact = UNITS; ktl = ktg - 12; }
  else               { M = U2; Kact = UNITS; ktl = ktg - 20; }
  int n = nt * 16 + (lane & 15);
  int kb = ktl * 32 + (lane >> 4) * 8;
  size_t base = fidx(ktg, nt, lane);
#pragma unroll
  for (int j = 0; j < 8; ++j) {
    int k = kb + j;
    wf[base + j] = (f16)((k < Kact) ? M[(size_t)k * UNITS + n] : 0.f);  // RNE
  }
}

// ---------------- precompute: emb -> padded fp16 (r10-verified) -------------
__global__ __launch_bounds__(256) void k_split_emb16(
    const float* __restrict__ emb, f16* __restrict__ ehf)
{
  int gid = blockIdx.x * 256 + threadIdx.x;
  if (gid >= 10000 * EMB_PAD) return;
  int row = gid >> 7, kk = gid & (EMB_PAD - 1);
  ehf[gid] = (f16)((kk < EMBD) ? emb[row * EMBD + kk] : 0.f);
}

#define MFMA16(A, B, C) __builtin_amdgcn_mfma_f32_16x16x32_f16(A, B, C, 0, 0, 0)

// store tanh result into next-step A-frag (single f16; layout r7-verified):
// elem (row=m, col=k): kt=col>>5, lane'=((col>>3)&3)*16+row, j'=col&7
__device__ __forceinline__ void store_frag1(f16* __restrict__ f, int col, int row, float v) {
  int a = (col >> 5) * 512 + (((col >> 3) & 3) * 16 + row) * 8 + (col & 7);
  f[a] = (f16)v;
}

// ---------------------------------------------------------------------------
// Main kernel v7 = r12 structure + the registers actually forced:
//  - amdgpu_waves_per_eu(4,4): exactly 1 block/CU, VGPR budget 512/wave, and
//    the occupancy heuristic (which chose 64 VGPR = 2 blocks/CU in r11/r12,
//    demoting the B-frags to per-step L2 reloads = 448 KB/CU-step) is pinned.
//  - asm-volatile pin on each B-frag: value's origin becomes the asm, so the
//    backend CANNOT rematerialize the load inside the t-loop.
// In-loop global traffic: 4-frag emb gather only (64 KB/CU-step).
// ---------------------------------------------------------------------------
__global__ __launch_bounds__(1024)
__attribute__((amdgpu_waves_per_eu(4, 4)))
void rnn_ws3(
    const int* __restrict__ idx, const f16* __restrict__ ehf,
    const f16* __restrict__ wf,
    const float* __restrict__ b1, const float* __restrict__ b2,
    float* __restrict__ out)
{
  __shared__ __align__(16) f16 f1[2][4096];   // [buf][kt*512 + lane*8 + j]
  __shared__ __align__(16) f16 f2[2][4096];

  const int tid  = threadIdx.x;
  const int lane = tid & 63;
  const int w    = tid >> 6;          // wave 0..15 = its n-tile
  const int m    = lane & 15;
  const int q    = lane >> 4;
  const int col0 = w * 16 + m;
  const int b0   = blockIdx.x * 16;

  const float bias1 = b1[col0];
  const float bias2 = b2[col0];
  const int* tokp = idx + (size_t)(b0 + m) * TLEN;

  // -------- persistent weight fragments: loaded once, pinned in VGPRs ------
  h8 Bx[4], Bu1[8], Bw2[8], Bu2[8];
#pragma unroll
  for (int kt = 0; kt < 4; ++kt) Bx[kt]  = *(const h8*)(wf + fidx(kt,      w, lane));
#pragma unroll
  for (int kt = 0; kt < 8; ++kt) Bu1[kt] = *(const h8*)(wf + fidx(4  + kt, w, lane));
#pragma unroll
  for (int kt = 0; kt < 8; ++kt) Bw2[kt] = *(const h8*)(wf + fidx(12 + kt, w, lane));
#pragma unroll
  for (int kt = 0; kt < 8; ++kt) Bu2[kt] = *(const h8*)(wf + fidx(20 + kt, w, lane));
  // pin: make values opaque -> no remat, must stay register-resident
#pragma unroll
  for (int kt = 0; kt < 4; ++kt) asm volatile("" : "+v"(Bx[kt]));
#pragma unroll
  for (int kt = 0; kt < 8; ++kt) asm volatile("" : "+v"(Bu1[kt]));
#pragma unroll
  for (int kt = 0; kt < 8; ++kt) asm volatile("" : "+v"(Bw2[kt]));
#pragma unroll
  for (int kt = 0; kt < 8; ++kt) asm volatile("" : "+v"(Bu2[kt]));

  // t=0 embedding fragment (A-operand rows = this lane's token row m)
  h8 Ax[4];
  {
    const f16* eh = ehf + (size_t)tokp[0] * EMB_PAD + q * 8;
#pragma unroll
    for (int kt = 0; kt < 4; ++kt) Ax[kt] = *(const h8*)(eh + kt * 32);
  }

  for (int i = tid; i < 4096; i += 1024) {
    f1[0][i] = (f16)0.f;
    f2[0][i] = (f16)0.f;
  }
  __syncthreads();

  for (int t = 0; t < TLEN; ++t) {
    const int p = t & 1, qb = p ^ 1;

    // ---- layer 1: a1 = b1 + x_t @ W1 + h1_old @ U1  (two indep chains) ----
    f32x4 accA = (f32x4){0.f, 0.f, 0.f, 0.f};
    f32x4 accB = (f32x4){0.f, 0.f, 0.f, 0.f};
#pragma unroll
    for (int kt = 0; kt < 4; ++kt)
      accA = MFMA16(Ax[kt], Bx[kt], accA);
#pragma unroll
    for (int kt = 0; kt < 8; ++kt) {
      h8 ah = *(const h8*)&f1[p][kt * 512 + lane * 8];
      if (kt & 1) accA = MFMA16(ah, Bu1[kt], accA);
      else        accB = MFMA16(ah, Bu1[kt], accB);
    }
#pragma unroll
    for (int r = 0; r < 4; ++r)
      store_frag1(f1[qb], col0, q * 4 + r, fast_tanh(accA[r] + accB[r] + bias1));

    // ---- layer 2 pre-barrier half: h2_old @ U2 (independent of f1[qb]) ----
    f32x4 acc2a = (f32x4){0.f, 0.f, 0.f, 0.f};
    f32x4 acc2b = (f32x4){0.f, 0.f, 0.f, 0.f};
#pragma unroll
    for (int kt = 0; kt < 8; ++kt) {
      h8 ah = *(const h8*)&f2[p][kt * 512 + lane * 8];
      if (kt & 1) acc2a = MFMA16(ah, Bu2[kt], acc2a);
      else        acc2b = MFMA16(ah, Bu2[kt], acc2b);
    }
    __syncthreads();                           // barrier 1: f1[qb] visible

    // ---- layer 2 post-barrier half: h1_new @ W2 ----
#pragma unroll
    for (int kt = 0; kt < 8; ++kt) {
      h8 ah = *(const h8*)&f1[qb][kt * 512 + lane * 8];
      if (kt & 1) acc2a = MFMA16(ah, Bw2[kt], acc2a);
      else        acc2b = MFMA16(ah, Bw2[kt], acc2b);
    }
    // prefetch next step's embedding fragment (hidden under epilogue+barrier)
    if (t + 1 < TLEN) {
      const f16* eh = ehf + (size_t)tokp[t + 1] * EMB_PAD + q * 8;
#pragma unroll
      for (int kt = 0; kt < 4; ++kt) Ax[kt] = *(const h8*)(eh + kt * 32);
    }
#pragma unroll
    for (int r = 0; r < 4; ++r) {
      int row = q * 4 + r;
      float tv = fast_tanh(acc2a[r] + acc2b[r] + bias2);
      store_frag1(f2[qb], col0, row, tv);
      if (t == TLEN - 1)
        out[(size_t)(b0 + row) * UNITS + col0] = fast_sigmoid(tv);
    }
    __syncthreads();                           // barrier 2: f2[qb] visible
  }
}

// ---------------------------------------------------------------------------
extern "C" void kernel_launch(void* const* d_in, const int* in_sizes, int n_in,
                              void* d_out, int out_size, void* d_ws, size_t ws_size,
                              hipStream_t stream)
{
  const int*   idx = (const int*)d_in[0];
  const float* emb = (const float*)d_in[1];
  const float* W1  = (const float*)d_in[2];
  const float* U1  = (const float*)d_in[3];
  const float* b1  = (const float*)d_in[4];
  const float* W2  = (const float*)d_in[5];
  const float* U2  = (const float*)d_in[6];
  const float* b2  = (const float*)d_in[7];
  // d_in[8] (Wd), d_in[9] (bd) dead in the reference output.
  float* out = (float*)d_out;

  // WS_NEED = 3.02 MB < 6.04 MB proven available (r7); < 4 MB L2 per XCD.
  f16* ehf = (f16*)((char*)d_ws + OFF_EHF);
  f16* wf  = (f16*)((char*)d_ws + OFF_WF);
  k_split_emb16<<<(10000 * EMB_PAD + 255) / 256, 256, 0, stream>>>(emb, ehf);
  k_split_w16<<<(KT_ALL * 16 * 64 + 255) / 256, 256, 0, stream>>>(W1, U1, W2, U2, wf);
  rnn_ws3<<<BATCH / 16, 1024, 0, stream>>>(idx, ehf, wf, b1, b2, out);
}